// Round 1
// baseline (6674.014 us; speedup 1.0000x reference)
//
#include <hip/hip_runtime.h>

typedef __attribute__((ext_vector_type(8))) short short8;
typedef __attribute__((ext_vector_type(4))) float f32x4;

#define DEV static __device__ __forceinline__

DEV unsigned short f2b(float f) {
    union { float f; unsigned u; } v; v.f = f;
    unsigned r = (v.u + 0x7FFFu + ((v.u >> 16) & 1u)) >> 16;
    return (unsigned short)r;
}
DEV float b2f(unsigned short s) {
    union { unsigned u; float f; } v; v.u = ((unsigned)s) << 16;
    return v.f;
}
DEV float sigm(float x) { return 1.0f / (1.0f + __expf(-x)); }

// ---------------- converts ----------------

__global__ void k_f2b(const float* __restrict__ src, unsigned short* __restrict__ dst, int n4) {
    int i = blockIdx.x * blockDim.x + threadIdx.x;
    if (i < n4) {
        float4 v = ((const float4*)src)[i];
        ushort4 o;
        o.x = f2b(v.x); o.y = f2b(v.y); o.z = f2b(v.z); o.w = f2b(v.w);
        ((ushort4*)dst)[i] = o;
    }
}

// dst[(4j+g)][k] = bf16(src[(g*1024+j)][k]); Kq = K/4
__global__ void k_perm(const float* __restrict__ src, unsigned short* __restrict__ dst, int Kq) {
    int i = blockIdx.x * blockDim.x + threadIdx.x;
    int total = 4096 * Kq;
    if (i >= total) return;
    int rp = i / Kq, kq = i - rp * Kq;
    int j = rp >> 2, g = rp & 3;
    float4 v = ((const float4*)src)[(size_t)(g * 1024 + j) * Kq + kq];
    ushort4 o;
    o.x = f2b(v.x); o.y = f2b(v.y); o.z = f2b(v.z); o.w = f2b(v.w);
    ((ushort4*)dst)[(size_t)rp * Kq + kq] = o;
}

__global__ void k_bias(const float* __restrict__ bi0, const float* __restrict__ bh0,
                       const float* __restrict__ bi1, const float* __restrict__ bh1,
                       float* __restrict__ d0, float* __restrict__ d1) {
    int i = blockIdx.x * blockDim.x + threadIdx.x;
    if (i < 4096) {
        int j = i >> 2, g = i & 3, s = g * 1024 + j;
        d0[i] = bi0[s] + bh0[s];
        d1[i] = bi1[s] + bh1[s];
    }
}

__global__ void k_init(const float* __restrict__ hx, const float* __restrict__ cx,
                       unsigned short* __restrict__ h0, unsigned short* __restrict__ h1,
                       float* __restrict__ c0, float* __restrict__ c1) {
    int i = blockIdx.x * blockDim.x + threadIdx.x;
    if (i < 131072) {
        h0[i] = f2b(hx[i]);
        h1[i] = f2b(hx[131072 + i]);
        c0[i] = cx[i];
        c1[i] = cx[131072 + i];
    }
}

// ---------------- xg GEMM: out[v][n] = sum_k A[row(v)][k] * W[n][k] ----------------
// A rows indexed b*256 + t; virtual row v = b*TC + dt -> actual = (v/TC)*256 + t0 + v%TC.
// 128x128 tile, 4 waves (2x2), each wave 64x64 = 4x4 mfma_16x16x32 frags. K-step 32.
__global__ __launch_bounds__(256) void k_gemm(
    const unsigned short* __restrict__ A, const unsigned short* __restrict__ W,
    unsigned short* __restrict__ out, int K, int t0, int TC) {
    __shared__ unsigned short ldsA[128 * 40];  // padded row: 32 data + 8 pad bf16 (80B)
    __shared__ unsigned short ldsB[128 * 40];
    const int tid = threadIdx.x;
    const int w = tid >> 6, l = tid & 63;
    const int wm = w >> 1, wn = w & 1;
    const int bm = blockIdx.x, bn = blockIdx.y;
    const int lr = l & 15, lk = (l >> 4) * 8;

    // staging geometry (per-thread constant)
    const int row0 = tid >> 2, inb = (tid & 3) << 4;  // rows 0..63, 16B chunk in 64B row
    const int row1 = row0 + 64;
    const int v0 = bm * 128 + row0, v1 = bm * 128 + row1;
    const size_t ar0 = (size_t)((v0 / TC) * 256 + t0 + (v0 % TC));
    const size_t ar1 = (size_t)((v1 / TC) * 256 + t0 + (v1 % TC));
    const size_t br0 = (size_t)(bn * 128 + row0);
    const size_t br1 = (size_t)(bn * 128 + row1);

    f32x4 acc[4][4];
#pragma unroll
    for (int a = 0; a < 4; a++)
#pragma unroll
        for (int b = 0; b < 4; b++) acc[a][b] = (f32x4){0.f, 0.f, 0.f, 0.f};

    for (int ks = 0; ks < K; ks += 32) {
        uint4 a0 = *(const uint4*)((const char*)A + (ar0 * K + ks) * 2 + inb);
        uint4 a1 = *(const uint4*)((const char*)A + (ar1 * K + ks) * 2 + inb);
        uint4 b0 = *(const uint4*)((const char*)W + (br0 * K + ks) * 2 + inb);
        uint4 b1 = *(const uint4*)((const char*)W + (br1 * K + ks) * 2 + inb);
        *(uint4*)((char*)ldsA + row0 * 80 + inb) = a0;
        *(uint4*)((char*)ldsA + row1 * 80 + inb) = a1;
        *(uint4*)((char*)ldsB + row0 * 80 + inb) = b0;
        *(uint4*)((char*)ldsB + row1 * 80 + inb) = b1;
        __syncthreads();
        short8 af[4], bf[4];
#pragma unroll
        for (int mt = 0; mt < 4; mt++)
            af[mt] = *(const short8*)((const char*)ldsA + (wm * 64 + mt * 16 + lr) * 80 + lk * 2);
#pragma unroll
        for (int nt = 0; nt < 4; nt++)
            bf[nt] = *(const short8*)((const char*)ldsB + (wn * 64 + nt * 16 + lr) * 80 + lk * 2);
#pragma unroll
        for (int mt = 0; mt < 4; mt++)
#pragma unroll
            for (int nt = 0; nt < 4; nt++)
                acc[mt][nt] = __builtin_amdgcn_mfma_f32_16x16x32_bf16(af[mt], bf[nt], acc[mt][nt], 0, 0, 0);
        __syncthreads();
    }

#pragma unroll
    for (int mt = 0; mt < 4; mt++)
#pragma unroll
        for (int nt = 0; nt < 4; nt++)
#pragma unroll
            for (int v4 = 0; v4 < 4; v4++) {
                int vr = bm * 128 + wm * 64 + mt * 16 + (l >> 4) * 4 + v4;
                int col = bn * 128 + wn * 64 + nt * 16 + lr;
                out[(size_t)vr * 4096 + col] = f2b(acc[mt][nt][v4]);
            }
}

// ---------------- fused recurrent step: gates GEMM + cell ----------------
// grid 256: wg -> (mblk 0..1: 64 batch rows, nblk 0..127: 8 hidden units = 32 gate cols)
// Stages its 32x1024 W_hh' slice in LDS (padded), streams h frags from global.
__global__ __launch_bounds__(256) void k_step(
    const unsigned short* __restrict__ Wh,     // [4096][1024] bf16, gate-interleaved rows
    const unsigned short* __restrict__ hprev, int hstride,   // bf16, row b at b*hstride
    const unsigned short* __restrict__ xg_t, int xgstride,   // bf16, + b*xgstride + col
    const float* __restrict__ bias,            // [4096] interleaved
    float* __restrict__ cbuf,                  // [128*1024] fp32, in/out
    unsigned short* __restrict__ hout, int hostride,
    float* __restrict__ xout, int xostride,    // nullable (layer-1 writes fp32 h to d_out)
    float* __restrict__ hfin, float* __restrict__ cfin) {    // nullable (last step)
    __shared__ unsigned short ldsW[32 * 1032];  // rows padded to 1032 bf16 (2064B)
    __shared__ float ldsG[64 * 33];
    const int tid = threadIdx.x;
    const int w = tid >> 6, l = tid & 63;
    const int mblk = (int)blockIdx.x >> 7;
    const int nblk = (int)blockIdx.x & 127;
    const int lr = l & 15, lk = (l >> 4) * 8;

    // stage W slice: 32 rows x 2048B
    {
        const char* gsrc = (const char*)(Wh + (size_t)nblk * 32 * 1024);
#pragma unroll
        for (int r = 0; r < 16; r++) {
            int c = r * 256 + tid;
            int row = c >> 7, inr = (c & 127) << 4;
            *(uint4*)((char*)ldsW + row * 2064 + inr) = *(const uint4*)(gsrc + (size_t)row * 2048 + inr);
        }
    }
    __syncthreads();

    const int m0 = mblk * 64 + w * 16;
    f32x4 acc0 = (f32x4){0.f, 0.f, 0.f, 0.f};
    f32x4 acc1 = (f32x4){0.f, 0.f, 0.f, 0.f};
    const char* arow = (const char*)hprev + ((size_t)(m0 + lr) * hstride + lk) * 2;
    const char* b0p = (const char*)ldsW + (size_t)lr * 2064 + lk * 2;
    const char* b1p = b0p + 16 * 2064;
#pragma unroll 8
    for (int kk = 0; kk < 32; kk++) {
        short8 a = *(const short8*)(arow + kk * 64);
        short8 b0 = *(const short8*)(b0p + kk * 64);
        short8 b1 = *(const short8*)(b1p + kk * 64);
        acc0 = __builtin_amdgcn_mfma_f32_16x16x32_bf16(a, b0, acc0, 0, 0, 0);
        acc1 = __builtin_amdgcn_mfma_f32_16x16x32_bf16(a, b1, acc1, 0, 0, 0);
    }
#pragma unroll
    for (int v4 = 0; v4 < 4; v4++) {
        int gr = w * 16 + (l >> 4) * 4 + v4;
        ldsG[gr * 33 + lr] = acc0[v4];
        ldsG[gr * 33 + 16 + lr] = acc1[v4];
    }
    __syncthreads();

    for (int u = tid; u < 512; u += 256) {
        int r = u >> 3, dj = u & 7;
        int b = mblk * 64 + r;
        int colg = nblk * 32 + dj * 4;
        int hu = nblk * 8 + dj;
        float4 bs = *(const float4*)(bias + colg);
        ushort4 xg4 = *(const ushort4*)(xg_t + (size_t)b * xgstride + colg);
        float p0 = ldsG[r * 33 + dj * 4 + 0] + b2f(xg4.x) + bs.x;
        float p1 = ldsG[r * 33 + dj * 4 + 1] + b2f(xg4.y) + bs.y;
        float p2 = ldsG[r * 33 + dj * 4 + 2] + b2f(xg4.z) + bs.z;
        float p3 = ldsG[r * 33 + dj * 4 + 3] + b2f(xg4.w) + bs.w;
        float ig = sigm(p0), fg = sigm(p1), gv = tanhf(p2), og = sigm(p3);
        int ci = b * 1024 + hu;
        float cn = fg * cbuf[ci] + ig * gv;
        cbuf[ci] = cn;
        float h = og * tanhf(cn);
        hout[(size_t)b * hostride + hu] = f2b(h);
        if (xout) xout[(size_t)b * xostride + hu] = h;
        if (hfin) { hfin[ci] = h; cfin[ci] = cn; }
    }
}

// ---------------- host ----------------

extern "C" void kernel_launch(void* const* d_in, const int* in_sizes, int n_in,
                              void* d_out, int out_size, void* d_ws, size_t ws_size,
                              hipStream_t stream) {
    const float* x    = (const float*)d_in[0];
    const float* hx0  = (const float*)d_in[1];
    const float* cx0  = (const float*)d_in[2];
    const float* Wih0 = (const float*)d_in[3];
    const float* Whh0 = (const float*)d_in[4];
    const float* bih0 = (const float*)d_in[5];
    const float* bhh0 = (const float*)d_in[6];
    const float* Wih1 = (const float*)d_in[7];
    const float* Whh1 = (const float*)d_in[8];
    const float* bih1 = (const float*)d_in[9];
    const float* bhh1 = (const float*)d_in[10];
    float* out = (float*)d_out;

    const int B = 128, T = 256, I = 256, H = 1024, G4 = 4096;

    char* p = (char*)d_ws;
    auto alloc = [&](size_t bytes) { char* r = p; p += (bytes + 255) & ~(size_t)255; return r; };
    unsigned short* xbf   = (unsigned short*)alloc((size_t)B * T * I * 2);
    unsigned short* Wih0p = (unsigned short*)alloc((size_t)G4 * I * 2);
    unsigned short* Whh0p = (unsigned short*)alloc((size_t)G4 * H * 2);
    unsigned short* Wih1p = (unsigned short*)alloc((size_t)G4 * H * 2);
    unsigned short* Whh1p = (unsigned short*)alloc((size_t)G4 * H * 2);
    float* bias0 = (float*)alloc(G4 * 4);
    float* bias1 = (float*)alloc(G4 * 4);
    unsigned short* y0   = (unsigned short*)alloc((size_t)B * T * H * 2);
    unsigned short* h0b  = (unsigned short*)alloc((size_t)B * H * 2);
    unsigned short* h1b0 = (unsigned short*)alloc((size_t)B * H * 2);
    unsigned short* h1b1 = (unsigned short*)alloc((size_t)B * H * 2);
    float* c0 = (float*)alloc((size_t)B * H * 4);
    float* c1 = (float*)alloc((size_t)B * H * 4);
    size_t fixed = (size_t)(p - (char*)d_ws);
    int TC = 256;
    while (TC > 1 && fixed + (size_t)B * TC * G4 * 2 + 256 > ws_size) TC >>= 1;
    unsigned short* xg = (unsigned short*)alloc((size_t)B * TC * G4 * 2);

    // converts
    k_f2b<<<(B * T * I / 4 + 255) / 256, 256, 0, stream>>>(x, xbf, B * T * I / 4);
    k_perm<<<(G4 * (I / 4) + 255) / 256, 256, 0, stream>>>(Wih0, Wih0p, I / 4);
    k_perm<<<(G4 * (H / 4) + 255) / 256, 256, 0, stream>>>(Whh0, Whh0p, H / 4);
    k_perm<<<(G4 * (H / 4) + 255) / 256, 256, 0, stream>>>(Wih1, Wih1p, H / 4);
    k_perm<<<(G4 * (H / 4) + 255) / 256, 256, 0, stream>>>(Whh1, Whh1p, H / 4);
    k_bias<<<16, 256, 0, stream>>>(bih0, bhh0, bih1, bhh1, bias0, bias1);
    k_init<<<512, 256, 0, stream>>>(hx0, cx0, h0b, h1b0, c0, c1);

    // ---- layer 0 ----
    for (int t0 = 0; t0 < T; t0 += TC) {
        k_gemm<<<dim3(TC, 32), 256, 0, stream>>>(xbf, Wih0p, xg, I, t0, TC);
        for (int dt = 0; dt < TC; dt++) {
            int t = t0 + dt;
            const unsigned short* hp = (t == 0) ? h0b : (y0 + (size_t)(t - 1) * H);
            int hs = (t == 0) ? H : T * H;
            k_step<<<256, 256, 0, stream>>>(Whh0p, hp, hs, xg + (size_t)dt * G4, TC * G4,
                                            bias0, c0, y0 + (size_t)t * H, T * H,
                                            nullptr, 0, nullptr, nullptr);
        }
    }
    // ---- layer 1 ----
    for (int t0 = 0; t0 < T; t0 += TC) {
        k_gemm<<<dim3(TC, 32), 256, 0, stream>>>(y0, Wih1p, xg, H, t0, TC);
        for (int dt = 0; dt < TC; dt++) {
            int t = t0 + dt;
            const unsigned short* hp = (t & 1) ? h1b1 : h1b0;
            unsigned short* ho = (t & 1) ? h1b0 : h1b1;
            bool last = (t == T - 1);
            k_step<<<256, 256, 0, stream>>>(Whh1p, hp, H, xg + (size_t)dt * G4, TC * G4,
                                            bias1, c1, ho, H,
                                            out + (size_t)t * H, T * H,
                                            last ? (out + (size_t)B * T * H) : nullptr,
                                            last ? (out + (size_t)B * T * H + (size_t)B * H) : nullptr);
        }
    }
}